// Round 1
// baseline (783.178 us; speedup 1.0000x reference)
//
#include <hip/hip_runtime.h>

#define BB 1024
#define TT 512
#define HH 64
#define NB 2   // batch elements per block

typedef _Float16 h2 __attribute__((ext_vector_type(2)));

// v_dot2_f32_f16: 2 f16 MACs, fp32 accumulate, one VALU instr
#if defined(__has_builtin)
#  if __has_builtin(__builtin_amdgcn_fdot2)
#    define FDOT2(a, b, c) __builtin_amdgcn_fdot2((a), (b), (c), false)
#  endif
#endif
#ifndef FDOT2
#  define FDOT2(a, b, c) ((c) + (float)(a).x * (float)(b).x + (float)(a).y * (float)(b).y)
#endif

__device__ __forceinline__ float sigmoidf_(float v) {
    return 1.0f / (1.0f + __expf(-v));
}
__device__ __forceinline__ float tanhf_(float v) {
    return fmaf(2.0f, sigmoidf_(2.0f * v), -1.0f);
}
__device__ __forceinline__ h2 mkh2(float a, float b) {
    h2 r; r.x = (_Float16)a; r.y = (_Float16)b; return r;
}

union F4H { float4 f; h2 h[4]; };

// Layer-pipelined fused LSTM, f16-dot2 edition.
// Phase 1: thread t owns rows {r, r+128} (r = t&127) of Whh0/Wih1/Whh1 for
// batch nb = t>>7. h kept in LDS as f16: each thread reads only 16 b128/step
// (vs 64 in the fp32/1-row version) and retires 2 MACs per VALU instr.
__global__ __launch_bounds__(256, 2)
void lstm_fused3(const float* __restrict__ x,     // [B,T] (I=1)
                 const float* __restrict__ Wih0,  // [256]
                 const float* __restrict__ Whh0,  // [256,64]
                 const float* __restrict__ bih0,  // [256]
                 const float* __restrict__ bhh0,  // [256]
                 const float* __restrict__ Wih1,  // [256,64]
                 const float* __restrict__ Whh1,  // [256,64]
                 const float* __restrict__ bih1,  // [256]
                 const float* __restrict__ bhh1,  // [256]
                 const float* __restrict__ Wfc,   // [64]
                 const float* __restrict__ bfc,   // [1]
                 float* __restrict__ out)         // [B]
{
    __shared__ float s_x[NB][TT];
    __shared__ __align__(16) _Float16 s_h0[NB][HH];
    __shared__ __align__(16) _Float16 s_h1[NB][HH];
    __shared__ float s_g0[NB][256];
    __shared__ float s_g1[NB][256];

    const int t  = threadIdx.x;
    const int b0 = blockIdx.x * NB;

    // ---- phase-1 mapping: batch nb1, rows r and r+128 ----
    const int nb1 = t >> 7;
    const int r   = t & 127;

    const float xw0_a   = Wih0[r];
    const float xw0_b   = Wih0[r + 128];
    const float bias0_a = bih0[r]       + bhh0[r];
    const float bias0_b = bih0[r + 128] + bhh0[r + 128];
    const float bias1_a = bih1[r]       + bhh1[r];
    const float bias1_b = bih1[r + 128] + bhh1[r + 128];

    // ---- weights -> packed f16 registers: 6 rows x 32 half2 = 192 VGPR ----
    h2 w0[2][32], wi1[2][32], w1[2][32];
#pragma unroll
    for (int rr = 0; rr < 2; ++rr) {
        const float4* p0 = (const float4*)(Whh0 + (r + 128 * rr) * HH);
        const float4* p1 = (const float4*)(Wih1 + (r + 128 * rr) * HH);
        const float4* p2 = (const float4*)(Whh1 + (r + 128 * rr) * HH);
#pragma unroll
        for (int q = 0; q < 16; ++q) {
            float4 a = p0[q];
            w0[rr][2 * q]     = mkh2(a.x, a.y);
            w0[rr][2 * q + 1] = mkh2(a.z, a.w);
            float4 b = p1[q];
            wi1[rr][2 * q]     = mkh2(b.x, b.y);
            wi1[rr][2 * q + 1] = mkh2(b.z, b.w);
            float4 c = p2[q];
            w1[rr][2 * q]     = mkh2(c.x, c.y);
            w1[rr][2 * q + 1] = mkh2(c.z, c.w);
        }
    }

    // ---- stage x rows for this block's NB batch elements (coalesced) ----
#pragma unroll
    for (int k = 0; k < (NB * TT) / 256; ++k) {
        int idx = t + 256 * k;
        int nb  = idx >> 9;      // / TT
        int pos = idx & (TT - 1);
        s_x[nb][pos] = x[(b0 + nb) * TT + pos];
    }

    // zero initial hidden state
    if (t < NB * HH) {
        (&s_h0[0][0])[t] = (_Float16)0.0f;
        (&s_h1[0][0])[t] = (_Float16)0.0f;
    }

    // cell state residency: t<128 -> layer0 (nb=t>>6, j=t&63)
    //                       t>=128 -> layer1 (nb=(t>>6)&1, j=t&63)
    float cst = 0.0f;

    __syncthreads();

    for (int s = 0; s <= TT; ++s) {
        // ---- phase 1: both layers' gate matvecs, all 256 threads ----
        {
            const int xs = (s < TT) ? s : (TT - 1);  // s==TT result discarded
            const float xv = s_x[nb1][xs];
            float a0a = fmaf(xw0_a, xv, bias0_a);
            float a0b = fmaf(xw0_b, xv, bias0_b);
            float axa = 0.0f, axb = 0.0f;
            float aha = bias1_a, ahb = bias1_b;

            const F4H* ph0 = (const F4H*)s_h0[nb1];
            const F4H* ph1 = (const F4H*)s_h1[nb1];
#pragma unroll
            for (int i = 0; i < 8; ++i) {
                F4H h0v = ph0[i];   // 8 f16 h0 elems, one ds_read_b128
                F4H h1v = ph1[i];   // 8 f16 h1 elems
#pragma unroll
                for (int k = 0; k < 4; ++k) {
                    const int idx = 4 * i + k;
                    a0a = FDOT2(w0[0][idx],  h0v.h[k], a0a);
                    a0b = FDOT2(w0[1][idx],  h0v.h[k], a0b);
                    axa = FDOT2(wi1[0][idx], h0v.h[k], axa);
                    axb = FDOT2(wi1[1][idx], h0v.h[k], axb);
                    aha = FDOT2(w1[0][idx],  h1v.h[k], aha);
                    ahb = FDOT2(w1[1][idx],  h1v.h[k], ahb);
                }
            }
            s_g0[nb1][r]       = a0a;
            s_g0[nb1][r + 128] = a0b;
            s_g1[nb1][r]       = axa + aha;
            s_g1[nb1][r + 128] = axb + ahb;
        }
        __syncthreads();

        // ---- phase 2: unit updates ----
        if (t < 128) {
            // layer 0, timestep s (skip at s==TT)
            if (s < TT) {
                const int nb = t >> 6;
                const int j  = t & 63;
                float gi = s_g0[nb][j];
                float gf = s_g0[nb][j + 64];
                float gg = s_g0[nb][j + 128];
                float go = s_g0[nb][j + 192];
                float i_ = sigmoidf_(gi);
                float f_ = sigmoidf_(gf);
                float g_ = tanhf_(gg);
                float o_ = sigmoidf_(go);
                cst = fmaf(f_, cst, i_ * g_);
                s_h0[nb][j] = (_Float16)(o_ * tanhf_(cst));
            }
        } else {
            // layer 1, timestep s-1 (skip at s==0)
            if (s >= 1) {
                const int nb = (t >> 6) & 1;
                const int j  = t & 63;
                float gi = s_g1[nb][j];
                float gf = s_g1[nb][j + 64];
                float gg = s_g1[nb][j + 128];
                float go = s_g1[nb][j + 192];
                float i_ = sigmoidf_(gi);
                float f_ = sigmoidf_(gf);
                float g_ = tanhf_(gg);
                float o_ = sigmoidf_(go);
                cst = fmaf(f_, cst, i_ * g_);
                s_h1[nb][j] = (_Float16)(o_ * tanhf_(cst));
            }
        }
        __syncthreads();
    }

    // ---- epilogue: out[b0+nb] = h1_last . Wfc + bfc ----
    if (t < NB * HH) {
        const int nb = t >> 6;
        const int j  = t & 63;
        float v = (float)s_h1[nb][j] * Wfc[j];
#pragma unroll
        for (int off = 32; off > 0; off >>= 1) {
            v += __shfl_down(v, off);
        }
        if (j == 0) out[b0 + nb] = v + bfc[0];
    }
}

extern "C" void kernel_launch(void* const* d_in, const int* in_sizes, int n_in,
                              void* d_out, int out_size, void* d_ws, size_t ws_size,
                              hipStream_t stream) {
    const float* x    = (const float*)d_in[0];
    const float* Wih0 = (const float*)d_in[1];
    const float* Whh0 = (const float*)d_in[2];
    const float* bih0 = (const float*)d_in[3];
    const float* bhh0 = (const float*)d_in[4];
    const float* Wih1 = (const float*)d_in[5];
    const float* Whh1 = (const float*)d_in[6];
    const float* bih1 = (const float*)d_in[7];
    const float* bhh1 = (const float*)d_in[8];
    const float* Wfc  = (const float*)d_in[9];
    const float* bfc  = (const float*)d_in[10];
    float* out = (float*)d_out;

    lstm_fused3<<<dim3(BB / NB), dim3(256), 0, stream>>>(
        x, Wih0, Whh0, bih0, bhh0, Wih1, Whh1, bih1, bhh1, Wfc, bfc, out);
}

// Round 2
// 490.936 us; speedup vs baseline: 1.5953x; 1.5953x over previous
//
#include <hip/hip_runtime.h>

#define BB 1024
#define TT 512
#define HH 64
#define NB 4            // batches per block
#define NTHR 512        // 8 waves

typedef _Float16 half8 __attribute__((ext_vector_type(8)));
typedef float f32x4 __attribute__((ext_vector_type(4)));

__device__ __forceinline__ float sigmoidf_(float v) {
    return 1.0f / (1.0f + __expf(-v));
}
__device__ __forceinline__ float tanhf_(float v) {
    return fmaf(2.0f, sigmoidf_(2.0f * v), -1.0f);
}

// A-fragment loader: element e of k-half kk = W[row][kk*32 + (lane>>4)*8 + e].
// The SAME (lane-group, e) -> k mapping is used for the B fragment, so the
// MFMA contraction is correct regardless of the HW's internal k permutation.
__device__ __forceinline__ half8 load_frag(const float* __restrict__ W, int row, int k0) {
    const float4* p = (const float4*)(W + row * HH + k0);
    float4 u = p[0], v = p[1];
    half8 r;
    r[0] = (_Float16)u.x; r[1] = (_Float16)u.y; r[2] = (_Float16)u.z; r[3] = (_Float16)u.w;
    r[4] = (_Float16)v.x; r[5] = (_Float16)v.y; r[6] = (_Float16)v.z; r[7] = (_Float16)v.w;
    return r;
}

// MFMA-based layer-pipelined fused LSTM.
// Phase 1: gates = W[256x64] x H[64xNB] on matrix cores. Wave w owns output
// tiles {2w, 2w+1} for layer-0 gates (Whh0 . h0) and for layer-1 gates
// (Wih1 . h0 + Whh1 . h1, 4 chained MFMAs into one accumulator).
// B cols 4..15 replicate batches 0..3 (harmless, results discarded on write).
// Phase 2: 1 unit-update per thread (2 layers x 4 batches x 64 units = 512).
__global__ __launch_bounds__(NTHR, 2)
void lstm_mfma(const float* __restrict__ x,     // [B,T] (I=1)
               const float* __restrict__ Wih0,  // [256]
               const float* __restrict__ Whh0,  // [256,64]
               const float* __restrict__ bih0,  // [256]
               const float* __restrict__ bhh0,  // [256]
               const float* __restrict__ Wih1,  // [256,64]
               const float* __restrict__ Whh1,  // [256,64]
               const float* __restrict__ bih1,  // [256]
               const float* __restrict__ bhh1,  // [256]
               const float* __restrict__ Wfc,   // [64]
               const float* __restrict__ bfc,   // [1]
               float* __restrict__ out)         // [B]
{
    __shared__ float s_x[NB][TT];                          // 8 KB
    __shared__ __align__(16) _Float16 s_h0[NB][80];        // padded rows
    __shared__ __align__(16) _Float16 s_h1[NB][80];
    __shared__ __align__(16) float s_g0[NB][260];          // layer0 gates
    __shared__ __align__(16) float s_g1[NB][260];          // layer1 gates

    const int t    = threadIdx.x;
    const int lane = t & 63;
    const int w    = t >> 6;          // wave 0..7
    const int b0   = blockIdx.x * NB;

    const int arow = lane & 15;       // A row within tile; D col (batch)
    const int g4   = lane >> 4;       // k-group 0..3
    const int bsrc = arow & 3;        // replicated batch for B operand

    // ---- one-time: A fragments into registers (48 VGPRs of f16) ----
    half8 a0[2][2], a1i[2][2], a1h[2][2];   // [tile][k-half]
#pragma unroll
    for (int d = 0; d < 2; ++d) {
        const int mrow = (2 * w + d) * 16 + arow;
#pragma unroll
        for (int kk = 0; kk < 2; ++kk) {
            const int k0 = kk * 32 + g4 * 8;
            a0[d][kk]  = load_frag(Whh0, mrow, k0);
            a1i[d][kk] = load_frag(Wih1, mrow, k0);
            a1h[d][kk] = load_frag(Whh1, mrow, k0);
        }
    }

    // ---- stage x (coalesced) ----
#pragma unroll
    for (int k = 0; k < (NB * TT) / NTHR; ++k) {
        int idx = t + NTHR * k;
        int nb  = idx >> 9;          // / TT
        int pos = idx & (TT - 1);
        s_x[nb][pos] = x[(b0 + nb) * TT + pos];
    }
    // zero initial hidden state (incl. padding)
    if (t < NB * 80) {
        (&s_h0[0][0])[t] = (_Float16)0.0f;
        (&s_h1[0][0])[t] = (_Float16)0.0f;
    }

    // ---- phase-2 mapping: thread -> (layer, batch, unit) ----
    const int layer = t >> 8;         // 0 or 1
    const int nb2   = (t >> 6) & 3;
    const int j     = t & 63;
    float xw[4], bs[4];
#pragma unroll
    for (int q = 0; q < 4; ++q) {
        int r = j + 64 * q;
        if (layer == 0) { xw[q] = Wih0[r]; bs[q] = bih0[r] + bhh0[r]; }
        else            { xw[q] = 0.0f;    bs[q] = bih1[r] + bhh1[r]; }
    }
    float cst = 0.0f;

    // B-fragment LDS addresses (element units; 16B aligned)
    const _Float16* h0p = &s_h0[bsrc][g4 * 8];
    const _Float16* h1p = &s_h1[bsrc][g4 * 8];

    __syncthreads();

    for (int s = 0; s <= TT; ++s) {
        // ---- phase 1: gate GEMMs on matrix cores ----
        {
            half8 bh0_0 = *(const half8*)(h0p);        // k 0..31
            half8 bh0_1 = *(const half8*)(h0p + 32);   // k 32..63
            half8 bh1_0 = *(const half8*)(h1p);
            half8 bh1_1 = *(const half8*)(h1p + 32);
#pragma unroll
            for (int d = 0; d < 2; ++d) {
                f32x4 c0 = {0.0f, 0.0f, 0.0f, 0.0f};
                f32x4 c1 = {0.0f, 0.0f, 0.0f, 0.0f};
                c0 = __builtin_amdgcn_mfma_f32_16x16x32_f16(a0[d][0],  bh0_0, c0, 0, 0, 0);
                c0 = __builtin_amdgcn_mfma_f32_16x16x32_f16(a0[d][1],  bh0_1, c0, 0, 0, 0);
                c1 = __builtin_amdgcn_mfma_f32_16x16x32_f16(a1i[d][0], bh0_0, c1, 0, 0, 0);
                c1 = __builtin_amdgcn_mfma_f32_16x16x32_f16(a1i[d][1], bh0_1, c1, 0, 0, 0);
                c1 = __builtin_amdgcn_mfma_f32_16x16x32_f16(a1h[d][0], bh1_0, c1, 0, 0, 0);
                c1 = __builtin_amdgcn_mfma_f32_16x16x32_f16(a1h[d][1], bh1_1, c1, 0, 0, 0);
                if (arow < 4) {   // D col = arow = batch; rows (lane>>4)*4+reg
                    const int row0 = (2 * w + d) * 16 + g4 * 4;
                    *(f32x4*)&s_g0[arow][row0] = c0;
                    *(f32x4*)&s_g1[arow][row0] = c1;
                }
            }
        }
        __syncthreads();

        // ---- phase 2: unit updates (1 task/thread) ----
        if (layer == 0) {
            if (s < TT) {    // layer 0 computes timestep s
                const float xv = s_x[nb2][s];
                float gi = fmaf(xw[0], xv, s_g0[nb2][j]       + bs[0]);
                float gf = fmaf(xw[1], xv, s_g0[nb2][j + 64]  + bs[1]);
                float gg = fmaf(xw[2], xv, s_g0[nb2][j + 128] + bs[2]);
                float go = fmaf(xw[3], xv, s_g0[nb2][j + 192] + bs[3]);
                float i_ = sigmoidf_(gi);
                float f_ = sigmoidf_(gf);
                float g_ = tanhf_(gg);
                float o_ = sigmoidf_(go);
                cst = fmaf(f_, cst, i_ * g_);
                s_h0[nb2][j] = (_Float16)(o_ * tanhf_(cst));
            }
        } else {
            if (s >= 1) {    // layer 1 computes timestep s-1
                float gi = s_g1[nb2][j]       + bs[0];
                float gf = s_g1[nb2][j + 64]  + bs[1];
                float gg = s_g1[nb2][j + 128] + bs[2];
                float go = s_g1[nb2][j + 192] + bs[3];
                float i_ = sigmoidf_(gi);
                float f_ = sigmoidf_(gf);
                float g_ = tanhf_(gg);
                float o_ = sigmoidf_(go);
                cst = fmaf(f_, cst, i_ * g_);
                s_h1[nb2][j] = (_Float16)(o_ * tanhf_(cst));
            }
        }
        __syncthreads();
    }

    // ---- epilogue: out[b] = h1_last . Wfc + bfc ----
    if (t < NB * HH) {
        const int nb = t >> 6;
        float v = (float)s_h1[nb][j] * Wfc[j];
#pragma unroll
        for (int off = 32; off > 0; off >>= 1) {
            v += __shfl_down(v, off);
        }
        if (j == 0) out[b0 + nb] = v + bfc[0];
    }
}

extern "C" void kernel_launch(void* const* d_in, const int* in_sizes, int n_in,
                              void* d_out, int out_size, void* d_ws, size_t ws_size,
                              hipStream_t stream) {
    const float* x    = (const float*)d_in[0];
    const float* Wih0 = (const float*)d_in[1];
    const float* Whh0 = (const float*)d_in[2];
    const float* bih0 = (const float*)d_in[3];
    const float* bhh0 = (const float*)d_in[4];
    const float* Wih1 = (const float*)d_in[5];
    const float* Whh1 = (const float*)d_in[6];
    const float* bih1 = (const float*)d_in[7];
    const float* bhh1 = (const float*)d_in[8];
    const float* Wfc  = (const float*)d_in[9];
    const float* bfc  = (const float*)d_in[10];
    float* out = (float*)d_out;

    lstm_mfma<<<dim3(BB / NB), dim3(NTHR), 0, stream>>>(
        x, Wih0, Whh0, bih0, bhh0, Wih1, Whh1, bih1, bhh1, Wfc, bfc, out);
}

// Round 3
// 317.740 us; speedup vs baseline: 2.4648x; 1.5451x over previous
//
#include <hip/hip_runtime.h>

#define BB 1024
#define TT 512
#define HH 64
#define NB 4            // batches per block
#define NTHR 512        // 8 waves

typedef _Float16 half8 __attribute__((ext_vector_type(8)));
typedef float f32x4 __attribute__((ext_vector_type(4)));

#if defined(__has_builtin)
#  if __has_builtin(__builtin_amdgcn_rcpf)
#    define FRCP(v) __builtin_amdgcn_rcpf(v)
#  endif
#endif
#ifndef FRCP
#  define FRCP(v) (1.0f / (v))
#endif

#define MFMA16(A, B, C) __builtin_amdgcn_mfma_f32_16x16x32_f16((A), (B), (C), 0, 0, 0)

__device__ __forceinline__ float fsig(float v) {
    return FRCP(1.0f + __expf(-v));   // v_exp + v_add + v_rcp
}
__device__ __forceinline__ float ftanh(float v) {
    return fmaf(2.0f, fsig(2.0f * v), -1.0f);
}

// A-fragment loader: element e of k-half = W[row][k0 + e]; same (lane-group,
// element)->k bijection as the B fragment, so the contraction is exact.
__device__ __forceinline__ half8 load_frag(const float* __restrict__ W, int row, int k0) {
    const float4* p = (const float4*)(W + row * HH + k0);
    float4 u = p[0], v = p[1];
    half8 r;
    r[0] = (_Float16)u.x; r[1] = (_Float16)u.y; r[2] = (_Float16)u.z; r[3] = (_Float16)u.w;
    r[4] = (_Float16)v.x; r[5] = (_Float16)v.y; r[6] = (_Float16)v.z; r[7] = (_Float16)v.w;
    return r;
}

// Register-resident MFMA LSTM.
// Row permutation: tile (w,d) within-tile row i <- W row (i&3)*64 + 8w+4d+(i>>2),
// so after the MFMA, lane (g4=lane>>4, col=lane&15) reg q holds gate q of unit
// u=8w+4d+g4 for batch col&3 (cols replicate batches 4x). The replica index
// col>>2 selects the lane's task: layer=rep>>1, tile d=rep&1 -> all 64 unique
// (layer,unit,batch) tasks per wave are finished lane-locally. No gate LDS
// round-trip; biases enter as MFMA C-in; ONE barrier per timestep with
// double-buffered h state.
__global__ __launch_bounds__(NTHR, 2)
void lstm_mfma2(const float* __restrict__ x,     // [B,T] (I=1)
                const float* __restrict__ Wih0,  // [256]
                const float* __restrict__ Whh0,  // [256,64]
                const float* __restrict__ bih0,  // [256]
                const float* __restrict__ bhh0,  // [256]
                const float* __restrict__ Wih1,  // [256,64]
                const float* __restrict__ Whh1,  // [256,64]
                const float* __restrict__ bih1,  // [256]
                const float* __restrict__ bhh1,  // [256]
                const float* __restrict__ Wfc,   // [64]
                const float* __restrict__ bfc,   // [1]
                float* __restrict__ out)         // [B]
{
    __shared__ float s_x[NB][TT + 1];                       // padded rows
    __shared__ __align__(16) _Float16 s_h0b[2][NB][80];     // double-buffered
    __shared__ __align__(16) _Float16 s_h1b[2][NB][80];

    const int t    = threadIdx.x;
    const int lane = t & 63;
    const int w    = t >> 6;          // wave 0..7
    const int b0   = blockIdx.x * NB;

    const int arow = lane & 15;       // A/B row within tile; D col
    const int g4   = lane >> 4;       // k-group 0..3
    const int bsrc = lane & 3;        // batch (replicated B cols)

    // task assignment from replica index
    const int rep   = (lane >> 2) & 3;
    const int layer = rep >> 1;       // 0 or 1
    const int dd    = rep & 1;        // which tile's gates this lane finishes
    const int u     = 8 * w + 4 * dd + g4;   // my unit

    // ---- one-time: A fragments (permuted rows) into registers ----
    half8 a0[2][2], a1i[2][2], a1h[2][2];   // [tile][k-half]
#pragma unroll
    for (int d = 0; d < 2; ++d) {
        const int row = (arow & 3) * 64 + 8 * w + 4 * d + (arow >> 2);
#pragma unroll
        for (int kk = 0; kk < 2; ++kk) {
            const int k0 = kk * 32 + g4 * 8;
            a0[d][kk]  = load_frag(Whh0, row, k0);
            a1i[d][kk] = load_frag(Wih1, row, k0);
            a1h[d][kk] = load_frag(Whh1, row, k0);
        }
    }

    // ---- biases as MFMA C-in: cb[d][q] = bias of gate q, unit 8w+4d+g4 ----
    f32x4 cb0[2], cb1[2];
#pragma unroll
    for (int d = 0; d < 2; ++d) {
        const int uu = 8 * w + 4 * d + g4;
#pragma unroll
        for (int q = 0; q < 4; ++q) {
            const int r = q * 64 + uu;
            cb0[d][q] = bih0[r] + bhh0[r];
            cb1[d][q] = bih1[r] + bhh1[r];
        }
    }
    // x weight for my task's 4 gates (layer-1 lanes: 0)
    float xw[4];
#pragma unroll
    for (int q = 0; q < 4; ++q) {
        xw[q] = (layer == 0) ? Wih0[q * 64 + u] : 0.0f;
    }

    // ---- stage x (coalesced) ----
#pragma unroll
    for (int k = 0; k < (NB * TT) / NTHR; ++k) {
        int idx = t + NTHR * k;
        int nb  = idx >> 9;          // / TT
        int pos = idx & (TT - 1);
        s_x[nb][pos] = x[(b0 + nb) * TT + pos];
    }
    // zero both h buffers
    {
        _Float16* z0 = &s_h0b[0][0][0];
        _Float16* z1 = &s_h1b[0][0][0];
        for (int i = t; i < 2 * NB * 80; i += NTHR) {
            z0[i] = (_Float16)0.0f;
            z1[i] = (_Float16)0.0f;
        }
    }

    float cst = 0.0f;   // my task's cell state
    __syncthreads();

    for (int s = 0; s <= TT; ++s) {
        const int rb = s & 1;        // read buffer
        const int wb = rb ^ 1;       // write buffer
        const int xs = (s < TT) ? s : (TT - 1);
        const float xv = s_x[bsrc][xs];

        const _Float16* h0p = &s_h0b[rb][bsrc][g4 * 8];
        const _Float16* h1p = &s_h1b[rb][bsrc][g4 * 8];
        half8 bh0_0 = *(const half8*)(h0p);        // k 0..31
        half8 bh0_1 = *(const half8*)(h0p + 32);   // k 32..63
        half8 bh1_0 = *(const half8*)(h1p);
        half8 bh1_1 = *(const half8*)(h1p + 32);

        // layer-0 gates (Whh0.h0 + bias0), 2-deep chains
        f32x4 c0_0 = cb0[0], c0_1 = cb0[1];
        c0_0 = MFMA16(a0[0][0], bh0_0, c0_0);
        c0_1 = MFMA16(a0[1][0], bh0_0, c0_1);
        c0_0 = MFMA16(a0[0][1], bh0_1, c0_0);
        c0_1 = MFMA16(a0[1][1], bh0_1, c0_1);
        // layer-1 gates (Wih1.h0 + Whh1.h1 + bias1), split accumulators
        f32x4 c1a0 = cb1[0], c1a1 = cb1[1];
        f32x4 c1b0 = {0.f, 0.f, 0.f, 0.f}, c1b1 = {0.f, 0.f, 0.f, 0.f};
        c1a0 = MFMA16(a1i[0][0], bh0_0, c1a0);
        c1a1 = MFMA16(a1i[1][0], bh0_0, c1a1);
        c1b0 = MFMA16(a1h[0][0], bh1_0, c1b0);
        c1b1 = MFMA16(a1h[1][0], bh1_0, c1b1);
        c1a0 = MFMA16(a1i[0][1], bh0_1, c1a0);
        c1a1 = MFMA16(a1i[1][1], bh0_1, c1a1);
        c1b0 = MFMA16(a1h[0][1], bh1_1, c1b0);
        c1b1 = MFMA16(a1h[1][1], bh1_1, c1b1);
        f32x4 c1_0 = c1a0 + c1b0;
        f32x4 c1_1 = c1a1 + c1b1;

        // lane-local task select (no shuffles, no LDS)
        f32x4 t0 = dd ? c0_1 : c0_0;
        f32x4 t1 = dd ? c1_1 : c1_0;
        f32x4 gv = layer ? t1 : t0;

        float gi = fmaf(xw[0], xv, gv[0]);
        float gf = fmaf(xw[1], xv, gv[1]);
        float gg = fmaf(xw[2], xv, gv[2]);
        float go = fmaf(xw[3], xv, gv[3]);

        const bool active = layer ? (s >= 1) : (s < TT);
        if (active) {
            float i_ = fsig(gi);
            float f_ = fsig(gf);
            float g_ = ftanh(gg);
            float o_ = fsig(go);
            cst = fmaf(f_, cst, i_ * g_);
            float hn = o_ * ftanh(cst);
            _Float16* dst = layer ? &s_h1b[wb][bsrc][u] : &s_h0b[wb][bsrc][u];
            *dst = (_Float16)hn;
        }
        __syncthreads();
    }

    // ---- epilogue: out[b] = h1_last . Wfc + bfc ----
    // last write (s=TT) went to buffer wb = (TT&1)^1 = 1
    if (t < NB * HH) {
        const int nb = t >> 6;
        const int j  = t & 63;
        float v = (float)s_h1b[1][nb][j] * Wfc[j];
#pragma unroll
        for (int off = 32; off > 0; off >>= 1) {
            v += __shfl_down(v, off);
        }
        if (j == 0) out[b0 + nb] = v + bfc[0];
    }
}

extern "C" void kernel_launch(void* const* d_in, const int* in_sizes, int n_in,
                              void* d_out, int out_size, void* d_ws, size_t ws_size,
                              hipStream_t stream) {
    const float* x    = (const float*)d_in[0];
    const float* Wih0 = (const float*)d_in[1];
    const float* Whh0 = (const float*)d_in[2];
    const float* bih0 = (const float*)d_in[3];
    const float* bhh0 = (const float*)d_in[4];
    const float* Wih1 = (const float*)d_in[5];
    const float* Whh1 = (const float*)d_in[6];
    const float* bih1 = (const float*)d_in[7];
    const float* bhh1 = (const float*)d_in[8];
    const float* Wfc  = (const float*)d_in[9];
    const float* bfc  = (const float*)d_in[10];
    float* out = (float*)d_out;

    lstm_mfma2<<<dim3(BB / NB), dim3(NTHR), 0, stream>>>(
        x, Wih0, Whh0, bih0, bhh0, Wih1, Whh1, bih1, bhh1, Wfc, bfc, out);
}